// Round 3
// baseline (1682.570 us; speedup 1.0000x reference)
//
#include <hip/hip_runtime.h>

#define BB 256
#define TT 2048
#define SS 32
#define NN 19
#define NCLASS 10
#define NUNFOLD 6
#define EPSV 1e-8f
#define LOG2E 1.4426950408889634f
#define CH 128                 // timesteps per producer chunk
#define NCH (TT / CH)          // 16 chunks
#define SROW 39                // sens row: 19 num + 19 den + 1 pad (bank-spread)

typedef float v2f __attribute__((ext_vector_type(2)));

// ---------------------------------------------------------------------------
template <int CTRL>
__device__ __forceinline__ float dpp_shl(float x)
{
    return __int_as_float(__builtin_amdgcn_update_dpp(
        0, __float_as_int(x), CTRL, 0xf, 0xf, true));
}

__device__ __forceinline__ float bperm(int addr4, float v)
{
    return __int_as_float(__builtin_amdgcn_ds_bpermute(addr4, __float_as_int(v)));
}

// leader lane of pre-neuron i (rows 2,3 offset +1 => all 19 leaders in
// distinct LDS banks -> conflict-free bpermute broadcast)
__device__ __forceinline__ int lead_lane(int i)
{
    int rw = i / 5;
    return 16 * rw + 3 * (i % 5) + (rw >= 2 ? 1 : 0);
}

// ---------------------------------------------------------------------------
// Wave 0 = scan chain (compacted bperm gather).  Waves 1-3 = producers.
// R3 vs R2: (a) gather for the NEXT unfold issues immediately after v is
// computed (pipelined across unfolds, timesteps, and chunks) so bookkeeping
// sits in the ~130cy bperm shadow; (b) leader lane SEEDS the accumulator
// with {cmt*v + nbase, dbase} (cndmask-guarded: non-leader lanes can have
// inf/NaN v), removing the post-DPP adds: tail = DPP -> rcp -> mul.
// ---------------------------------------------------------------------------
template <int KU>
__device__ __forceinline__ void fused_loop(
    int tid, int lane, int wid, int b, int jc, bool lead0,
    const float (&sg2)[8], const float (&sb2)[8],
    const float (&Aa)[8], const float (&Wm)[8], const int (&src4)[8],
    float cmt, float glvl, float cgl, float ow0, float ob0,
    const float* __restrict__ x,
    const float4* __restrict__ pq,   // LDS: folded sensory params [j*SS+s]
    float* __restrict__ sbuf,        // LDS: [2][CH][SROW]
    float* __restrict__ obuf)        // LDS: [TT] motor outputs
{
    constexpr int NP = KU / 2;

    // packed per-lane constants: sig-arg pairs + {Aa,Wm} channel pairs
    v2f sgv[NP > 0 ? NP : 1], sbv[NP > 0 ? NP : 1], AW[KU];
#pragma unroll
    for (int p = 0; p < NP; p++) {
        sgv[p].x = sg2[2 * p];     sgv[p].y = sg2[2 * p + 1];
        sbv[p].x = sb2[2 * p];     sbv[p].y = sb2[2 * p + 1];
    }
#pragma unroll
    for (int k = 0; k < KU; k++) {
        AW[k].x = Aa[k];           AW[k].y = Wm[k];
    }

    float v = 0.f;
    float vi[KU];                    // gathered pre-neuron v's (one ahead)
#pragma unroll
    for (int k = 0; k < KU; k++) vi[k] = 0.f;   // gather of v=0

    for (int c = 0; c <= NCH; c++) {
        if (wid != 0) {
            if (c < NCH) {               // produce chunk c
                float* sb = sbuf + (c & 1) * (CH * SROW);
                const float* xb = x + ((long)b * TT + (long)c * CH) * SS;
                for (int tl = tid - 64; tl < CH; tl += 192) {
                    const float4* xr4 = (const float4*)(xb + tl * SS);
                    float xs[SS];
#pragma unroll
                    for (int q = 0; q < SS / 4; q++) {
                        float4 v4 = xr4[q];
                        xs[4 * q + 0] = v4.x; xs[4 * q + 1] = v4.y;
                        xs[4 * q + 2] = v4.z; xs[4 * q + 3] = v4.w;
                    }
                    float* srow = sb + tl * SROW;
                    for (int j = 0; j < NN; j++) {      // wave-uniform j
                        const float4* pp = pq + j * SS;
                        float num = 0.f, den = 0.f;
#pragma unroll 4
                        for (int s = 0; s < SS; s += 2) {
                            float4 c0 = pp[s];          // broadcast (uniform)
                            float4 c1 = pp[s + 1];
                            float e0 = __builtin_amdgcn_exp2f(fmaf(c0.y, xs[s], c0.x));
                            float e1 = __builtin_amdgcn_exp2f(fmaf(c1.y, xs[s + 1], c1.x));
                            float t0v = 1.0f + e0, t1v = 1.0f + e1;
                            float rD = __builtin_amdgcn_rcpf(t0v * t1v);
                            num = fmaf(fmaf(c0.w, t1v, c1.w * t0v), rD, num);
                            den = fmaf(fmaf(c0.z, t1v, c1.z * t0v), rD, den);
                        }
                        srow[j]      = num;             // stride-39 rows:
                        srow[NN + j] = den;             // 2-way banks = free
                    }
                }
            }
        } else if (c > 0) {              // scan chunk c-1
            const float* sb = sbuf + ((c - 1) & 1) * (CH * SROW);
            float sn = sb[jc], sd = sb[NN + jc];
            int tbase = (c - 1) * CH;
            for (int tl = 0; tl < CH; tl++) {
                float sn_nx = sn, sd_nx = sd;
                if (tl + 1 < CH) {       // prefetch (hidden by 6 unfolds)
                    sn_nx = sb[(tl + 1) * SROW + jc];
                    sd_nx = sb[(tl + 1) * SROW + NN + jc];
                }
                // per-tl bases; leader-only seeds (guarded against non-lead
                // lanes' degenerate v: their pw must be exactly {0,0})
                float nbs = glvl + sn;
                float dbs = lead0 ? (cgl + sd) : 0.f;
                float sdx = lead0 ? fmaf(cmt, v, nbs) : 0.f;
#pragma unroll
                for (int u = 0; u < NUNFOLD; u++) {
                    v2f pw;                              // seeded accumulator
                    pw.x = sdx;
                    pw.y = dbs;
                    float ev[KU];
#pragma unroll
                    for (int p = 0; p < NP; p++) {       // packed sig args
                        v2f viP;
                        viP.x = vi[2 * p]; viP.y = vi[2 * p + 1];
                        v2f arg = sgv[p] * viP + sbv[p]; // v_pk_fma_f32
                        ev[2 * p]     = __builtin_amdgcn_exp2f(arg.x);
                        ev[2 * p + 1] = __builtin_amdgcn_exp2f(arg.y);
                    }
                    if (KU & 1)
                        ev[KU - 1] = __builtin_amdgcn_exp2f(
                            fmaf(sg2[KU - 1], vi[KU - 1], sb2[KU - 1]));
#pragma unroll
                    for (int p = 0; p < NP; p++) {
                        float t0v = 1.0f + ev[2 * p];
                        float t1v = 1.0f + ev[2 * p + 1];
                        float rD  = __builtin_amdgcn_rcpf(t0v * t1v);
                        v2f cmb = AW[2 * p] * t1v + AW[2 * p + 1] * t0v;
                        pw = cmb * rD + pw;              // v_pk_fma_f32
                    }
                    if (KU & 1) {
                        float s1 = __builtin_amdgcn_rcpf(1.0f + ev[KU - 1]);
                        pw = AW[KU - 1] * s1 + pw;
                    }
                    // 3-lane DPP reduce, tree form: leader gets full sums
                    float pn = pw.x, pd = pw.y;
                    float an = dpp_shl<0x101>(pn), bn = dpp_shl<0x102>(pn);
                    float ad = dpp_shl<0x101>(pd), bd = dpp_shl<0x102>(pd);
                    pn += an + bn;
                    pd += ad + bd;
                    // seeded: pn == cmt*v + nbase + Σnum, pd == dbase + Σden
                    v = pn * __builtin_amdgcn_rcpf(pd);
                    // issue NEXT unfold's gather immediately (chain head);
                    // everything below sits in its ~130cy shadow
#pragma unroll
                    for (int k = 0; k < KU; k++) vi[k] = bperm(src4[k], v);
                    if (u + 1 < NUNFOLD)
                        sdx = lead0 ? fmaf(cmt, v, nbs) : 0.f;
                }
                if (lane == 0) obuf[tbase + tl] = fmaf(v, ow0, ob0);
                sn = sn_nx; sd = sd_nx;
            }
        }
        __syncthreads();
    }
}

// ---------------------------------------------------------------------------
// One block per batch element.  Wave 0 scans; waves 1-3 produce; all 4 waves
// run the FC epilogue from LDS.
// ---------------------------------------------------------------------------
__global__ void __launch_bounds__(256, 1)
ltc_fused_kernel(const float* __restrict__ x,
                 const float* __restrict__ iw,  const float* __restrict__ ib,
                 const float* __restrict__ smu, const float* __restrict__ ssig,
                 const float* __restrict__ sw,  const float* __restrict__ serev,
                 const int* __restrict__ smask,
                 const float* __restrict__ mu,  const float* __restrict__ sigma,
                 const float* __restrict__ w,   const float* __restrict__ erev,
                 const int* __restrict__ mask,
                 const float* __restrict__ gleak, const float* __restrict__ vleak,
                 const float* __restrict__ cm,
                 const float* __restrict__ ow,  const float* __restrict__ ob,
                 const float* __restrict__ fcw, const float* __restrict__ fcb,
                 float* __restrict__ out)
{
    __shared__ float4 pq[SS * NN];          // 9.7 KB folded sensory params
    __shared__ float  sbuf[2 * CH * SROW];  // 39.9 KB sens ring (stride 39)
    __shared__ float  obuf[TT];             // 8 KB motor outputs
    __shared__ float  red[4 * NCLASS];      // FC cross-wave reduce

    int tid  = threadIdx.x;
    int b    = blockIdx.x;
    int lane = tid & 63;
    int wid  = tid >> 6;

    // ---- fold sensory params into LDS: pq[j*SS+s] = {P, Qn, W, A} ----
    for (int idx = tid; idx < SS * NN; idx += 256) {
        int j = idx >> 5;
        int s = idx & 31;
        int src = s * NN + j;
        float sg = ssig[src] * LOG2E;
        float P  = sg * smu[src] - sg * ib[s];
        float Qn = -sg * iw[s];
        float wm = sw[src] * (float)smask[src];
        pq[idx] = make_float4(P, Qn, wm, wm * serev[src]);
    }

    // ---- scan-lane setup (replicated on all waves; depends only on lane,
    //      so every wave derives the identical km for uniform control) ----
    int row  = lane >> 4;
    int pos  = lane & 15;
    int off  = (row >= 2) ? 1 : 0;
    int posr = pos - off;
    int jq   = (posr < 0) ? 5 : posr / 3;
    int rr   = (posr < 0) ? 0 : posr - 3 * jq;
    int j    = row * 5 + jq;
    bool pad = (jq >= 5) || (j >= NN);
    int jc   = pad ? 0 : j;
    int r    = pad ? 0 : rr;
    bool lead0 = (r == 0) && !pad;

    float sg2[8], sb2[8], Aa[8], Wm[8];
    int src4[8];
    int used = 0;
#pragma unroll
    for (int s = 0; s < 8; s++) {
        int target = 3 * s + r;
        int ii = -1, a = 0;
        for (int i = 0; i < NN; i++) {
            if (mask[i * NN + jc] != 0) {
                if (a == target) ii = i;
                a++;
            }
        }
        bool ok = (ii >= 0) && !pad;
        int iu  = ok ? ii : 0;
        int idx = iu * NN + jc;
        float sgv = sigma[idx];
        float wmm = ok ? w[idx] : 0.f;
        sg2[s] = ok ? (-LOG2E * sgv) : 0.f;
        sb2[s] = ok ? (LOG2E * sgv * mu[idx]) : 0.f;
        Aa[s]  = wmm * erev[idx];
        Wm[s]  = wmm;
        src4[s] = lead_lane(iu) << 2;
        if (ok) used = s + 1;
    }
    int km = used;
#pragma unroll
    for (int o = 1; o < 64; o <<= 1) {
        int other = __shfl_xor(km, o, 64);
        km = km > other ? km : other;
    }

    float cmt   = cm[jc] * (float)NUNFOLD;
    float gl    = gleak[jc];
    float glvl  = gl * vleak[jc];
    float cgl   = cmt + gl + EPSV;
    float ow0 = ow[0], ob0 = ob[0];

    __syncthreads();   // pq ready before producers start chunk 0

    if (km <= 3)
        fused_loop<3>(tid, lane, wid, b, jc, lead0, sg2, sb2, Aa, Wm, src4,
                      cmt, glvl, cgl, ow0, ob0, x, pq, sbuf, obuf);
    else if (km == 4)
        fused_loop<4>(tid, lane, wid, b, jc, lead0, sg2, sb2, Aa, Wm, src4,
                      cmt, glvl, cgl, ow0, ob0, x, pq, sbuf, obuf);
    else if (km == 5)
        fused_loop<5>(tid, lane, wid, b, jc, lead0, sg2, sb2, Aa, Wm, src4,
                      cmt, glvl, cgl, ow0, ob0, x, pq, sbuf, obuf);
    else if (km == 6)
        fused_loop<6>(tid, lane, wid, b, jc, lead0, sg2, sb2, Aa, Wm, src4,
                      cmt, glvl, cgl, ow0, ob0, x, pq, sbuf, obuf);
    else
        fused_loop<7>(tid, lane, wid, b, jc, lead0, sg2, sb2, Aa, Wm, src4,
                      cmt, glvl, cgl, ow0, ob0, x, pq, sbuf, obuf);

    // ---- FC epilogue: out[b][c] = sum_t obuf[t]*fcw[c][t] + fcb[c] ----
    float acc[NCLASS];
#pragma unroll
    for (int c = 0; c < NCLASS; c++) acc[c] = 0.f;
    for (int t = tid; t < TT; t += 256) {
        float ov = obuf[t];
#pragma unroll
        for (int c = 0; c < NCLASS; c++)
            acc[c] = fmaf(ov, fcw[c * TT + t], acc[c]);
    }
#pragma unroll
    for (int c = 0; c < NCLASS; c++) {
#pragma unroll
        for (int o2 = 32; o2 > 0; o2 >>= 1)
            acc[c] += __shfl_down(acc[c], o2, 64);
    }
    if (lane == 0) {
#pragma unroll
        for (int c = 0; c < NCLASS; c++) red[wid * NCLASS + c] = acc[c];
    }
    __syncthreads();
    if (tid < NCLASS)
        out[b * NCLASS + tid] = red[tid] + red[NCLASS + tid]
                              + red[2 * NCLASS + tid] + red[3 * NCLASS + tid]
                              + fcb[tid];
}

// ---------------------------------------------------------------------------
extern "C" void kernel_launch(void* const* d_in, const int* in_sizes, int n_in,
                              void* d_out, int out_size, void* d_ws, size_t ws_size,
                              hipStream_t stream)
{
    const float* x     = (const float*)d_in[0];
    const float* iw    = (const float*)d_in[1];
    const float* ib    = (const float*)d_in[2];
    const float* smu   = (const float*)d_in[3];
    const float* ssig  = (const float*)d_in[4];
    const float* sw    = (const float*)d_in[5];
    const float* serev = (const float*)d_in[6];
    const float* mu    = (const float*)d_in[7];
    const float* sigma = (const float*)d_in[8];
    const float* w     = (const float*)d_in[9];
    const float* erev  = (const float*)d_in[10];
    const float* gleak = (const float*)d_in[11];
    const float* vleak = (const float*)d_in[12];
    const float* cm    = (const float*)d_in[13];
    const float* ow    = (const float*)d_in[14];
    const float* ob    = (const float*)d_in[15];
    const float* fcw   = (const float*)d_in[16];
    const float* fcb   = (const float*)d_in[17];
    const int* smask   = (const int*)d_in[18];
    const int* mask    = (const int*)d_in[19];
    float* out = (float*)d_out;

    ltc_fused_kernel<<<BB, 256, 0, stream>>>(x, iw, ib, smu, ssig, sw, serev,
                                             smask, mu, sigma, w, erev, mask,
                                             gleak, vleak, cm, ow, ob,
                                             fcw, fcb, out);
}

// Round 4
// 1672.531 us; speedup vs baseline: 1.0060x; 1.0060x over previous
//
#include <hip/hip_runtime.h>

#define BB 256
#define TT 2048
#define SS 32
#define NN 19
#define NCLASS 10
#define NUNFOLD 6
#define EPSV 1e-8f
#define LOG2E 1.4426950408889634f
#define CH 128                 // timesteps per producer chunk
#define NCH (TT / CH)          // 16 chunks
#define SROW 39                // sens row: 19 num + 19 den + 1 pad (bank-spread)

typedef float v2f __attribute__((ext_vector_type(2)));

// ---------------------------------------------------------------------------
template <int CTRL>
__device__ __forceinline__ float dpp_shl(float x)
{
    return __int_as_float(__builtin_amdgcn_update_dpp(
        0, __float_as_int(x), CTRL, 0xf, 0xf, true));
}

__device__ __forceinline__ float bperm(int addr4, float v)
{
    return __int_as_float(__builtin_amdgcn_ds_bpermute(addr4, __float_as_int(v)));
}

// leader lane of pre-neuron i (rows 2,3 offset +1 => all 19 leaders in
// distinct LDS banks -> conflict-free bpermute broadcast)
__device__ __forceinline__ int lead_lane(int i)
{
    int rw = i / 5;
    return 16 * rw + 3 * (i % 5) + (rw >= 2 ? 1 : 0);
}

// ---------------------------------------------------------------------------
// Wave 0 = scan chain (compacted bperm gather).  Waves 1-3 = producers.
// R4 vs R3 (chain diet -- every edit removes cycles from the serial ring):
//   (a) two-accumulator tree for pw (pwA seeded / pwB) kills the serial
//       pair-accumulation chain;
//   (b) DPP tail = 2 serial dpp-adds (pn+shl1, +shl2(pn)) not dpp,dpp,add,add;
//   (c) pd reduced FIRST so rcp(pd3) overlaps pn's DPP tail.
// ---------------------------------------------------------------------------
template <int KU>
__device__ __forceinline__ void fused_loop(
    int tid, int lane, int wid, int b, int jc, bool lead0,
    const float (&sg2)[8], const float (&sb2)[8],
    const float (&Aa)[8], const float (&Wm)[8], const int (&src4)[8],
    float cmt, float glvl, float cgl, float ow0, float ob0,
    const float* __restrict__ x,
    const float4* __restrict__ pq,   // LDS: folded sensory params [j*SS+s]
    float* __restrict__ sbuf,        // LDS: [2][CH][SROW]
    float* __restrict__ obuf)        // LDS: [TT] motor outputs
{
    constexpr int NP = KU / 2;

    // packed per-lane constants: sig-arg pairs + {Aa,Wm} channel pairs
    v2f sgv[NP > 0 ? NP : 1], sbv[NP > 0 ? NP : 1], AW[KU];
#pragma unroll
    for (int p = 0; p < NP; p++) {
        sgv[p].x = sg2[2 * p];     sgv[p].y = sg2[2 * p + 1];
        sbv[p].x = sb2[2 * p];     sbv[p].y = sb2[2 * p + 1];
    }
#pragma unroll
    for (int k = 0; k < KU; k++) {
        AW[k].x = Aa[k];           AW[k].y = Wm[k];
    }

    float v = 0.f;
    float vi[KU];                    // gathered pre-neuron v's (one ahead)
#pragma unroll
    for (int k = 0; k < KU; k++) vi[k] = 0.f;   // gather of v=0

    for (int c = 0; c <= NCH; c++) {
        if (wid != 0) {
            if (c < NCH) {               // produce chunk c
                float* sb = sbuf + (c & 1) * (CH * SROW);
                const float* xb = x + ((long)b * TT + (long)c * CH) * SS;
                for (int tl = tid - 64; tl < CH; tl += 192) {
                    const float4* xr4 = (const float4*)(xb + tl * SS);
                    float xs[SS];
#pragma unroll
                    for (int q = 0; q < SS / 4; q++) {
                        float4 v4 = xr4[q];
                        xs[4 * q + 0] = v4.x; xs[4 * q + 1] = v4.y;
                        xs[4 * q + 2] = v4.z; xs[4 * q + 3] = v4.w;
                    }
                    float* srow = sb + tl * SROW;
                    for (int j = 0; j < NN; j++) {      // wave-uniform j
                        const float4* pp = pq + j * SS;
                        float num = 0.f, den = 0.f;
#pragma unroll 4
                        for (int s = 0; s < SS; s += 2) {
                            float4 c0 = pp[s];          // broadcast (uniform)
                            float4 c1 = pp[s + 1];
                            float e0 = __builtin_amdgcn_exp2f(fmaf(c0.y, xs[s], c0.x));
                            float e1 = __builtin_amdgcn_exp2f(fmaf(c1.y, xs[s + 1], c1.x));
                            float t0v = 1.0f + e0, t1v = 1.0f + e1;
                            float rD = __builtin_amdgcn_rcpf(t0v * t1v);
                            num = fmaf(fmaf(c0.w, t1v, c1.w * t0v), rD, num);
                            den = fmaf(fmaf(c0.z, t1v, c1.z * t0v), rD, den);
                        }
                        srow[j]      = num;             // stride-39 rows:
                        srow[NN + j] = den;             // 2-way banks = free
                    }
                }
            }
        } else if (c > 0) {              // scan chunk c-1
            const float* sb = sbuf + ((c - 1) & 1) * (CH * SROW);
            float sn = sb[jc], sd = sb[NN + jc];
            int tbase = (c - 1) * CH;
            for (int tl = 0; tl < CH; tl++) {
                float sn_nx = sn, sd_nx = sd;
                if (tl + 1 < CH) {       // prefetch (hidden by 6 unfolds)
                    sn_nx = sb[(tl + 1) * SROW + jc];
                    sd_nx = sb[(tl + 1) * SROW + NN + jc];
                }
                // per-tl bases; leader-only seeds (guarded against non-lead
                // lanes' degenerate v: their pw must be exactly {0,0})
                float nbs = glvl + sn;
                float dbs = lead0 ? (cgl + sd) : 0.f;
                float sdx = lead0 ? fmaf(cmt, v, nbs) : 0.f;
#pragma unroll
                for (int u = 0; u < NUNFOLD; u++) {
                    float ev[KU];
#pragma unroll
                    for (int p = 0; p < NP; p++) {       // packed sig args
                        v2f viP;
                        viP.x = vi[2 * p]; viP.y = vi[2 * p + 1];
                        v2f arg = sgv[p] * viP + sbv[p]; // v_pk_fma_f32
                        ev[2 * p]     = __builtin_amdgcn_exp2f(arg.x);
                        ev[2 * p + 1] = __builtin_amdgcn_exp2f(arg.y);
                    }
                    if (KU & 1)
                        ev[KU - 1] = __builtin_amdgcn_exp2f(
                            fmaf(sg2[KU - 1], vi[KU - 1], sb2[KU - 1]));
                    // two-accumulator tree: pwA seeded, pwB independent
                    v2f pwA, pwB;
                    pwA.x = sdx;  pwA.y = dbs;
                    pwB.x = 0.f;  pwB.y = 0.f;
#pragma unroll
                    for (int p = 0; p < NP; p++) {
                        float t0v = 1.0f + ev[2 * p];
                        float t1v = 1.0f + ev[2 * p + 1];
                        float rD  = __builtin_amdgcn_rcpf(t0v * t1v);
                        v2f cmb = AW[2 * p] * t1v + AW[2 * p + 1] * t0v;
                        if (p & 1) pwB = cmb * rD + pwB; // v_pk_fma_f32
                        else       pwA = cmb * rD + pwA;
                    }
                    if (KU & 1) {
                        float s1 = __builtin_amdgcn_rcpf(1.0f + ev[KU - 1]);
                        pwB = AW[KU - 1] * s1 + pwB;
                    }
                    v2f pw = pwA + pwB;                  // single combine
                    // pd reduced FIRST: its rcp overlaps pn's DPP tail
                    float pd = pw.y, pn = pw.x;
                    float pd2 = pd + dpp_shl<0x101>(pd);
                    float pd3 = pd2 + dpp_shl<0x102>(pd);
                    float rpd = __builtin_amdgcn_rcpf(pd3);
                    float pn2 = pn + dpp_shl<0x101>(pn);
                    float pn3 = pn2 + dpp_shl<0x102>(pn);
                    // seeded: pn3 == cmt*v + nbase + Σnum, pd3 == dbase + Σden
                    v = pn3 * rpd;
                    // issue NEXT unfold's gather immediately (chain head)
#pragma unroll
                    for (int k = 0; k < KU; k++) vi[k] = bperm(src4[k], v);
                    if (u + 1 < NUNFOLD)
                        sdx = lead0 ? fmaf(cmt, v, nbs) : 0.f;
                }
                if (lane == 0) obuf[tbase + tl] = fmaf(v, ow0, ob0);
                sn = sn_nx; sd = sd_nx;
            }
        }
        __syncthreads();
    }
}

// ---------------------------------------------------------------------------
// One block per batch element.  Wave 0 scans; waves 1-3 produce; all 4 waves
// run the FC epilogue from LDS.
// ---------------------------------------------------------------------------
__global__ void __launch_bounds__(256, 1)
ltc_fused_kernel(const float* __restrict__ x,
                 const float* __restrict__ iw,  const float* __restrict__ ib,
                 const float* __restrict__ smu, const float* __restrict__ ssig,
                 const float* __restrict__ sw,  const float* __restrict__ serev,
                 const int* __restrict__ smask,
                 const float* __restrict__ mu,  const float* __restrict__ sigma,
                 const float* __restrict__ w,   const float* __restrict__ erev,
                 const int* __restrict__ mask,
                 const float* __restrict__ gleak, const float* __restrict__ vleak,
                 const float* __restrict__ cm,
                 const float* __restrict__ ow,  const float* __restrict__ ob,
                 const float* __restrict__ fcw, const float* __restrict__ fcb,
                 float* __restrict__ out)
{
    __shared__ float4 pq[SS * NN];          // 9.7 KB folded sensory params
    __shared__ float  sbuf[2 * CH * SROW];  // 39.9 KB sens ring (stride 39)
    __shared__ float  obuf[TT];             // 8 KB motor outputs
    __shared__ float  red[4 * NCLASS];      // FC cross-wave reduce

    int tid  = threadIdx.x;
    int b    = blockIdx.x;
    int lane = tid & 63;
    int wid  = tid >> 6;

    // ---- fold sensory params into LDS: pq[j*SS+s] = {P, Qn, W, A} ----
    for (int idx = tid; idx < SS * NN; idx += 256) {
        int j = idx >> 5;
        int s = idx & 31;
        int src = s * NN + j;
        float sg = ssig[src] * LOG2E;
        float P  = sg * smu[src] - sg * ib[s];
        float Qn = -sg * iw[s];
        float wm = sw[src] * (float)smask[src];
        pq[idx] = make_float4(P, Qn, wm, wm * serev[src]);
    }

    // ---- scan-lane setup (replicated on all waves; depends only on lane,
    //      so every wave derives the identical km for uniform control) ----
    int row  = lane >> 4;
    int pos  = lane & 15;
    int off  = (row >= 2) ? 1 : 0;
    int posr = pos - off;
    int jq   = (posr < 0) ? 5 : posr / 3;
    int rr   = (posr < 0) ? 0 : posr - 3 * jq;
    int j    = row * 5 + jq;
    bool pad = (jq >= 5) || (j >= NN);
    int jc   = pad ? 0 : j;
    int r    = pad ? 0 : rr;
    bool lead0 = (r == 0) && !pad;

    float sg2[8], sb2[8], Aa[8], Wm[8];
    int src4[8];
    int used = 0;
#pragma unroll
    for (int s = 0; s < 8; s++) {
        int target = 3 * s + r;
        int ii = -1, a = 0;
        for (int i = 0; i < NN; i++) {
            if (mask[i * NN + jc] != 0) {
                if (a == target) ii = i;
                a++;
            }
        }
        bool ok = (ii >= 0) && !pad;
        int iu  = ok ? ii : 0;
        int idx = iu * NN + jc;
        float sgv = sigma[idx];
        float wmm = ok ? w[idx] : 0.f;
        sg2[s] = ok ? (-LOG2E * sgv) : 0.f;
        sb2[s] = ok ? (LOG2E * sgv * mu[idx]) : 0.f;
        Aa[s]  = wmm * erev[idx];
        Wm[s]  = wmm;
        src4[s] = lead_lane(iu) << 2;
        if (ok) used = s + 1;
    }
    int km = used;
#pragma unroll
    for (int o = 1; o < 64; o <<= 1) {
        int other = __shfl_xor(km, o, 64);
        km = km > other ? km : other;
    }

    float cmt   = cm[jc] * (float)NUNFOLD;
    float gl    = gleak[jc];
    float glvl  = gl * vleak[jc];
    float cgl   = cmt + gl + EPSV;
    float ow0 = ow[0], ob0 = ob[0];

    __syncthreads();   // pq ready before producers start chunk 0

    if (km <= 3)
        fused_loop<3>(tid, lane, wid, b, jc, lead0, sg2, sb2, Aa, Wm, src4,
                      cmt, glvl, cgl, ow0, ob0, x, pq, sbuf, obuf);
    else if (km == 4)
        fused_loop<4>(tid, lane, wid, b, jc, lead0, sg2, sb2, Aa, Wm, src4,
                      cmt, glvl, cgl, ow0, ob0, x, pq, sbuf, obuf);
    else if (km == 5)
        fused_loop<5>(tid, lane, wid, b, jc, lead0, sg2, sb2, Aa, Wm, src4,
                      cmt, glvl, cgl, ow0, ob0, x, pq, sbuf, obuf);
    else if (km == 6)
        fused_loop<6>(tid, lane, wid, b, jc, lead0, sg2, sb2, Aa, Wm, src4,
                      cmt, glvl, cgl, ow0, ob0, x, pq, sbuf, obuf);
    else
        fused_loop<7>(tid, lane, wid, b, jc, lead0, sg2, sb2, Aa, Wm, src4,
                      cmt, glvl, cgl, ow0, ob0, x, pq, sbuf, obuf);

    // ---- FC epilogue: out[b][c] = sum_t obuf[t]*fcw[c][t] + fcb[c] ----
    float acc[NCLASS];
#pragma unroll
    for (int c = 0; c < NCLASS; c++) acc[c] = 0.f;
    for (int t = tid; t < TT; t += 256) {
        float ov = obuf[t];
#pragma unroll
        for (int c = 0; c < NCLASS; c++)
            acc[c] = fmaf(ov, fcw[c * TT + t], acc[c]);
    }
#pragma unroll
    for (int c = 0; c < NCLASS; c++) {
#pragma unroll
        for (int o2 = 32; o2 > 0; o2 >>= 1)
            acc[c] += __shfl_down(acc[c], o2, 64);
    }
    if (lane == 0) {
#pragma unroll
        for (int c = 0; c < NCLASS; c++) red[wid * NCLASS + c] = acc[c];
    }
    __syncthreads();
    if (tid < NCLASS)
        out[b * NCLASS + tid] = red[tid] + red[NCLASS + tid]
                              + red[2 * NCLASS + tid] + red[3 * NCLASS + tid]
                              + fcb[tid];
}

// ---------------------------------------------------------------------------
extern "C" void kernel_launch(void* const* d_in, const int* in_sizes, int n_in,
                              void* d_out, int out_size, void* d_ws, size_t ws_size,
                              hipStream_t stream)
{
    const float* x     = (const float*)d_in[0];
    const float* iw    = (const float*)d_in[1];
    const float* ib    = (const float*)d_in[2];
    const float* smu   = (const float*)d_in[3];
    const float* ssig  = (const float*)d_in[4];
    const float* sw    = (const float*)d_in[5];
    const float* serev = (const float*)d_in[6];
    const float* mu    = (const float*)d_in[7];
    const float* sigma = (const float*)d_in[8];
    const float* w     = (const float*)d_in[9];
    const float* erev  = (const float*)d_in[10];
    const float* gleak = (const float*)d_in[11];
    const float* vleak = (const float*)d_in[12];
    const float* cm    = (const float*)d_in[13];
    const float* ow    = (const float*)d_in[14];
    const float* ob    = (const float*)d_in[15];
    const float* fcw   = (const float*)d_in[16];
    const float* fcb   = (const float*)d_in[17];
    const int* smask   = (const int*)d_in[18];
    const int* mask    = (const int*)d_in[19];
    float* out = (float*)d_out;

    ltc_fused_kernel<<<BB, 256, 0, stream>>>(x, iw, ib, smu, ssig, sw, serev,
                                             smask, mu, sigma, w, erev, mask,
                                             gleak, vleak, cm, ow, ob,
                                             fcw, fcb, out);
}

// Round 5
// 1646.729 us; speedup vs baseline: 1.0218x; 1.0157x over previous
//
#include <hip/hip_runtime.h>

#define BB 256
#define TT 2048
#define SS 32
#define NN 19
#define NCLASS 10
#define NUNFOLD 6
#define EPSV 1e-8f
#define LOG2E 1.4426950408889634f
#define CH 128                 // timesteps per producer chunk
#define NCH (TT / CH)          // 16 chunks
#define SROW 39                // sens row: 19 num + 19 den + 1 pad (bank-spread)

typedef float v2f __attribute__((ext_vector_type(2)));

// ---------------------------------------------------------------------------
template <int CTRL>
__device__ __forceinline__ float dpp_shl(float x)
{
    return __int_as_float(__builtin_amdgcn_update_dpp(
        0, __float_as_int(x), CTRL, 0xf, 0xf, true));
}

__device__ __forceinline__ float bperm(int addr4, float v)
{
    return __int_as_float(__builtin_amdgcn_ds_bpermute(addr4, __float_as_int(v)));
}

// leader lane of pre-neuron i (rows 2,3 offset +1 => all 19 leaders in
// distinct LDS banks -> conflict-free bpermute broadcast)
__device__ __forceinline__ int lead_lane(int i)
{
    int rw = i / 5;
    return 16 * rw + 3 * (i % 5) + (rw >= 2 ? 1 : 0);
}

// ---------------------------------------------------------------------------
// Common-denominator group combiners: Σ_k AW_k·sig_k over a group sharing
// ONE rcp.  t_k = 1 + 2^(σ(μ-v)·log2e); sig_k = 1/t_k.  Extra muls hide in
// the trans-pipe shadow; each saved rcp is ~8cy of quarter-rate pipe.
// Magnitudes: t ≤ ~150, quad denom ≤ 5e8 -- safe in f32.
// ---------------------------------------------------------------------------
template <int A>
__device__ __forceinline__ v2f comb2(const v2f* AW, const float* t)
{
    float rD = __builtin_amdgcn_rcpf(t[A] * t[A + 1]);
    v2f n = AW[A] * t[A + 1] + AW[A + 1] * t[A];
    return n * rD;
}

template <int A>
__device__ __forceinline__ v2f comb3(const v2f* AW, const float* t)
{
    float m12 = t[A + 1] * t[A + 2];
    float rD  = __builtin_amdgcn_rcpf(t[A] * m12);
    v2f inner = AW[A + 1] * t[A + 2] + AW[A + 2] * t[A + 1];
    v2f n     = AW[A] * m12 + inner * t[A];
    return n * rD;
}

template <int A>
__device__ __forceinline__ v2f comb4(const v2f* AW, const float* t)
{
    float t01 = t[A] * t[A + 1];
    float t23 = t[A + 2] * t[A + 3];
    float rD  = __builtin_amdgcn_rcpf(t01 * t23);
    v2f n01 = AW[A] * t[A + 1] + AW[A + 1] * t[A];
    v2f n23 = AW[A + 2] * t[A + 3] + AW[A + 3] * t[A + 2];
    v2f n   = n01 * t23 + n23 * t01;
    return n * rD;
}

// ---------------------------------------------------------------------------
// Wave 0 = scan chain (compacted bperm gather).  Waves 1-3 = producers.
// R5 vs R4: trans-pipe diet.  Per-unfold trans ops 9 -> 7 (KU=5) via
// wide common denominators: KU=3/4 -> 1 group rcp, KU=5/6/7 -> 2.  The
// pair/triple/quad numerator muls are VALU and hide under the trans ops.
// ---------------------------------------------------------------------------
template <int KU>
__device__ __forceinline__ void fused_loop(
    int tid, int lane, int wid, int b, int jc, bool lead0,
    const float (&sg2)[8], const float (&sb2)[8],
    const float (&Aa)[8], const float (&Wm)[8], const int (&src4)[8],
    float cmt, float glvl, float cgl, float ow0, float ob0,
    const float* __restrict__ x,
    const float4* __restrict__ pq,   // LDS: folded sensory params [j*SS+s]
    float* __restrict__ sbuf,        // LDS: [2][CH][SROW]
    float* __restrict__ obuf)        // LDS: [TT] motor outputs
{
    constexpr int NP = KU / 2;

    // packed per-lane constants: sig-arg pairs + {Aa,Wm} channel pairs
    v2f sgv[NP > 0 ? NP : 1], sbv[NP > 0 ? NP : 1], AW[KU];
#pragma unroll
    for (int p = 0; p < NP; p++) {
        sgv[p].x = sg2[2 * p];     sgv[p].y = sg2[2 * p + 1];
        sbv[p].x = sb2[2 * p];     sbv[p].y = sb2[2 * p + 1];
    }
#pragma unroll
    for (int k = 0; k < KU; k++) {
        AW[k].x = Aa[k];           AW[k].y = Wm[k];
    }

    float v = 0.f;
    float vi[KU];                    // gathered pre-neuron v's (one ahead)
#pragma unroll
    for (int k = 0; k < KU; k++) vi[k] = 0.f;   // gather of v=0

    for (int c = 0; c <= NCH; c++) {
        if (wid != 0) {
            if (c < NCH) {               // produce chunk c
                float* sb = sbuf + (c & 1) * (CH * SROW);
                const float* xb = x + ((long)b * TT + (long)c * CH) * SS;
                for (int tl = tid - 64; tl < CH; tl += 192) {
                    const float4* xr4 = (const float4*)(xb + tl * SS);
                    float xs[SS];
#pragma unroll
                    for (int q = 0; q < SS / 4; q++) {
                        float4 v4 = xr4[q];
                        xs[4 * q + 0] = v4.x; xs[4 * q + 1] = v4.y;
                        xs[4 * q + 2] = v4.z; xs[4 * q + 3] = v4.w;
                    }
                    float* srow = sb + tl * SROW;
                    for (int j = 0; j < NN; j++) {      // wave-uniform j
                        const float4* pp = pq + j * SS;
                        float num = 0.f, den = 0.f;
#pragma unroll 4
                        for (int s = 0; s < SS; s += 2) {
                            float4 c0 = pp[s];          // broadcast (uniform)
                            float4 c1 = pp[s + 1];
                            float e0 = __builtin_amdgcn_exp2f(fmaf(c0.y, xs[s], c0.x));
                            float e1 = __builtin_amdgcn_exp2f(fmaf(c1.y, xs[s + 1], c1.x));
                            float t0v = 1.0f + e0, t1v = 1.0f + e1;
                            float rD = __builtin_amdgcn_rcpf(t0v * t1v);
                            num = fmaf(fmaf(c0.w, t1v, c1.w * t0v), rD, num);
                            den = fmaf(fmaf(c0.z, t1v, c1.z * t0v), rD, den);
                        }
                        srow[j]      = num;             // stride-39 rows:
                        srow[NN + j] = den;             // 2-way banks = free
                    }
                }
            }
        } else if (c > 0) {              // scan chunk c-1
            const float* sb = sbuf + ((c - 1) & 1) * (CH * SROW);
            float sn = sb[jc], sd = sb[NN + jc];
            int tbase = (c - 1) * CH;
            for (int tl = 0; tl < CH; tl++) {
                float sn_nx = sn, sd_nx = sd;
                if (tl + 1 < CH) {       // prefetch (hidden by 6 unfolds)
                    sn_nx = sb[(tl + 1) * SROW + jc];
                    sd_nx = sb[(tl + 1) * SROW + NN + jc];
                }
                // per-tl bases; leader-only seeds (guarded against non-lead
                // lanes' degenerate v: their pw must be exactly {0,0})
                float nbs = glvl + sn;
                float dbs = lead0 ? (cgl + sd) : 0.f;
                float sdx = lead0 ? fmaf(cmt, v, nbs) : 0.f;
#pragma unroll
                for (int u = 0; u < NUNFOLD; u++) {
                    float ev[KU];
#pragma unroll
                    for (int p = 0; p < NP; p++) {       // packed sig args
                        v2f viP;
                        viP.x = vi[2 * p]; viP.y = vi[2 * p + 1];
                        v2f arg = sgv[p] * viP + sbv[p]; // v_pk_fma_f32
                        ev[2 * p]     = __builtin_amdgcn_exp2f(arg.x);
                        ev[2 * p + 1] = __builtin_amdgcn_exp2f(arg.y);
                    }
                    if (KU & 1)
                        ev[KU - 1] = __builtin_amdgcn_exp2f(
                            fmaf(sg2[KU - 1], vi[KU - 1], sb2[KU - 1]));
                    float tt[KU];
#pragma unroll
                    for (int k = 0; k < KU; k++) tt[k] = 1.0f + ev[k];
                    // seeded accumulator + wide-denominator groups
                    v2f seed;
                    seed.x = sdx;  seed.y = dbs;
                    v2f pw;
                    if constexpr (KU == 3)
                        pw = seed + comb3<0>(AW, tt);
                    else if constexpr (KU == 4)
                        pw = seed + comb4<0>(AW, tt);
                    else if constexpr (KU == 5)
                        pw = (seed + comb2<0>(AW, tt)) + comb3<2>(AW, tt);
                    else if constexpr (KU == 6)
                        pw = (seed + comb3<0>(AW, tt)) + comb3<3>(AW, tt);
                    else
                        pw = (seed + comb3<0>(AW, tt)) + comb4<3>(AW, tt);
                    // pd reduced FIRST: its rcp overlaps pn's DPP tail
                    float pd = pw.y, pn = pw.x;
                    float pd2 = pd + dpp_shl<0x101>(pd);
                    float pd3 = pd2 + dpp_shl<0x102>(pd);
                    float rpd = __builtin_amdgcn_rcpf(pd3);
                    float pn2 = pn + dpp_shl<0x101>(pn);
                    float pn3 = pn2 + dpp_shl<0x102>(pn);
                    // seeded: pn3 == cmt*v + nbase + Σnum, pd3 == dbase + Σden
                    v = pn3 * rpd;
                    // issue NEXT unfold's gather immediately (chain head)
#pragma unroll
                    for (int k = 0; k < KU; k++) vi[k] = bperm(src4[k], v);
                    if (u + 1 < NUNFOLD)
                        sdx = lead0 ? fmaf(cmt, v, nbs) : 0.f;
                }
                if (lane == 0) obuf[tbase + tl] = fmaf(v, ow0, ob0);
                sn = sn_nx; sd = sd_nx;
            }
        }
        __syncthreads();
    }
}

// ---------------------------------------------------------------------------
// One block per batch element.  Wave 0 scans; waves 1-3 produce; all 4 waves
// run the FC epilogue from LDS.
// ---------------------------------------------------------------------------
__global__ void __launch_bounds__(256, 1)
ltc_fused_kernel(const float* __restrict__ x,
                 const float* __restrict__ iw,  const float* __restrict__ ib,
                 const float* __restrict__ smu, const float* __restrict__ ssig,
                 const float* __restrict__ sw,  const float* __restrict__ serev,
                 const int* __restrict__ smask,
                 const float* __restrict__ mu,  const float* __restrict__ sigma,
                 const float* __restrict__ w,   const float* __restrict__ erev,
                 const int* __restrict__ mask,
                 const float* __restrict__ gleak, const float* __restrict__ vleak,
                 const float* __restrict__ cm,
                 const float* __restrict__ ow,  const float* __restrict__ ob,
                 const float* __restrict__ fcw, const float* __restrict__ fcb,
                 float* __restrict__ out)
{
    __shared__ float4 pq[SS * NN];          // 9.7 KB folded sensory params
    __shared__ float  sbuf[2 * CH * SROW];  // 39.9 KB sens ring (stride 39)
    __shared__ float  obuf[TT];             // 8 KB motor outputs
    __shared__ float  red[4 * NCLASS];      // FC cross-wave reduce

    int tid  = threadIdx.x;
    int b    = blockIdx.x;
    int lane = tid & 63;
    int wid  = tid >> 6;

    // ---- fold sensory params into LDS: pq[j*SS+s] = {P, Qn, W, A} ----
    for (int idx = tid; idx < SS * NN; idx += 256) {
        int j = idx >> 5;
        int s = idx & 31;
        int src = s * NN + j;
        float sg = ssig[src] * LOG2E;
        float P  = sg * smu[src] - sg * ib[s];
        float Qn = -sg * iw[s];
        float wm = sw[src] * (float)smask[src];
        pq[idx] = make_float4(P, Qn, wm, wm * serev[src]);
    }

    // ---- scan-lane setup (replicated on all waves; depends only on lane,
    //      so every wave derives the identical km for uniform control) ----
    int row  = lane >> 4;
    int pos  = lane & 15;
    int off  = (row >= 2) ? 1 : 0;
    int posr = pos - off;
    int jq   = (posr < 0) ? 5 : posr / 3;
    int rr   = (posr < 0) ? 0 : posr - 3 * jq;
    int j    = row * 5 + jq;
    bool pad = (jq >= 5) || (j >= NN);
    int jc   = pad ? 0 : j;
    int r    = pad ? 0 : rr;
    bool lead0 = (r == 0) && !pad;

    float sg2[8], sb2[8], Aa[8], Wm[8];
    int src4[8];
    int used = 0;
#pragma unroll
    for (int s = 0; s < 8; s++) {
        int target = 3 * s + r;
        int ii = -1, a = 0;
        for (int i = 0; i < NN; i++) {
            if (mask[i * NN + jc] != 0) {
                if (a == target) ii = i;
                a++;
            }
        }
        bool ok = (ii >= 0) && !pad;
        int iu  = ok ? ii : 0;
        int idx = iu * NN + jc;
        float sgv = sigma[idx];
        float wmm = ok ? w[idx] : 0.f;
        sg2[s] = ok ? (-LOG2E * sgv) : 0.f;
        sb2[s] = ok ? (LOG2E * sgv * mu[idx]) : 0.f;
        Aa[s]  = wmm * erev[idx];
        Wm[s]  = wmm;
        src4[s] = lead_lane(iu) << 2;
        if (ok) used = s + 1;
    }
    int km = used;
#pragma unroll
    for (int o = 1; o < 64; o <<= 1) {
        int other = __shfl_xor(km, o, 64);
        km = km > other ? km : other;
    }

    float cmt   = cm[jc] * (float)NUNFOLD;
    float gl    = gleak[jc];
    float glvl  = gl * vleak[jc];
    float cgl   = cmt + gl + EPSV;
    float ow0 = ow[0], ob0 = ob[0];

    __syncthreads();   // pq ready before producers start chunk 0

    if (km <= 3)
        fused_loop<3>(tid, lane, wid, b, jc, lead0, sg2, sb2, Aa, Wm, src4,
                      cmt, glvl, cgl, ow0, ob0, x, pq, sbuf, obuf);
    else if (km == 4)
        fused_loop<4>(tid, lane, wid, b, jc, lead0, sg2, sb2, Aa, Wm, src4,
                      cmt, glvl, cgl, ow0, ob0, x, pq, sbuf, obuf);
    else if (km == 5)
        fused_loop<5>(tid, lane, wid, b, jc, lead0, sg2, sb2, Aa, Wm, src4,
                      cmt, glvl, cgl, ow0, ob0, x, pq, sbuf, obuf);
    else if (km == 6)
        fused_loop<6>(tid, lane, wid, b, jc, lead0, sg2, sb2, Aa, Wm, src4,
                      cmt, glvl, cgl, ow0, ob0, x, pq, sbuf, obuf);
    else
        fused_loop<7>(tid, lane, wid, b, jc, lead0, sg2, sb2, Aa, Wm, src4,
                      cmt, glvl, cgl, ow0, ob0, x, pq, sbuf, obuf);

    // ---- FC epilogue: out[b][c] = sum_t obuf[t]*fcw[c][t] + fcb[c] ----
    float acc[NCLASS];
#pragma unroll
    for (int c = 0; c < NCLASS; c++) acc[c] = 0.f;
    for (int t = tid; t < TT; t += 256) {
        float ov = obuf[t];
#pragma unroll
        for (int c = 0; c < NCLASS; c++)
            acc[c] = fmaf(ov, fcw[c * TT + t], acc[c]);
    }
#pragma unroll
    for (int c = 0; c < NCLASS; c++) {
#pragma unroll
        for (int o2 = 32; o2 > 0; o2 >>= 1)
            acc[c] += __shfl_down(acc[c], o2, 64);
    }
    if (lane == 0) {
#pragma unroll
        for (int c = 0; c < NCLASS; c++) red[wid * NCLASS + c] = acc[c];
    }
    __syncthreads();
    if (tid < NCLASS)
        out[b * NCLASS + tid] = red[tid] + red[NCLASS + tid]
                              + red[2 * NCLASS + tid] + red[3 * NCLASS + tid]
                              + fcb[tid];
}

// ---------------------------------------------------------------------------
extern "C" void kernel_launch(void* const* d_in, const int* in_sizes, int n_in,
                              void* d_out, int out_size, void* d_ws, size_t ws_size,
                              hipStream_t stream)
{
    const float* x     = (const float*)d_in[0];
    const float* iw    = (const float*)d_in[1];
    const float* ib    = (const float*)d_in[2];
    const float* smu   = (const float*)d_in[3];
    const float* ssig  = (const float*)d_in[4];
    const float* sw    = (const float*)d_in[5];
    const float* serev = (const float*)d_in[6];
    const float* mu    = (const float*)d_in[7];
    const float* sigma = (const float*)d_in[8];
    const float* w     = (const float*)d_in[9];
    const float* erev  = (const float*)d_in[10];
    const float* gleak = (const float*)d_in[11];
    const float* vleak = (const float*)d_in[12];
    const float* cm    = (const float*)d_in[13];
    const float* ow    = (const float*)d_in[14];
    const float* ob    = (const float*)d_in[15];
    const float* fcw   = (const float*)d_in[16];
    const float* fcb   = (const float*)d_in[17];
    const int* smask   = (const int*)d_in[18];
    const int* mask    = (const int*)d_in[19];
    float* out = (float*)d_out;

    ltc_fused_kernel<<<BB, 256, 0, stream>>>(x, iw, ib, smu, ssig, sw, serev,
                                             smask, mu, sigma, w, erev, mask,
                                             gleak, vleak, cm, ow, ob,
                                             fcw, fcb, out);
}